// Round 5
// baseline (46.377 us; speedup 1.0000x reference)
//
#include <hip/hip_runtime.h>

typedef __attribute__((ext_vector_type(8))) _Float16 half8;
typedef __attribute__((ext_vector_type(2))) _Float16 half2v;
typedef __attribute__((ext_vector_type(4))) float f32x4;
typedef __attribute__((ext_vector_type(4))) unsigned int uint4v;

namespace {
constexpr int kB = 2048;
constexpr int kF = 64;
constexpr int kC = 10;
constexpr int kS = 5;
constexpr int kG = kC + kS;          // 15 groups
constexpr int kH1 = 32;
constexpr int kH2 = 16;
constexpr float kWCat = 0.7f / kC;
constexpr float kWSub = 0.3f / kS;
constexpr int kThreads = 256;        // 4 waves
constexpr int kRowsPerBlock = 64;    // 4 waves x one 16-row MFMA tile
constexpr int kChunks = kB / kRowsPerBlock;    // 32 -> 2048 blocks

// ws layout (element offsets):
// wsA f32  [960][72]: [kg*16+0..7]=w1[kg*8+j], [kg*16+8..15]=b1[kg*8+j], [64]=wgt*b3
constexpr int kARec = 72;
// wsB u16  [960][512]: lane l, j: fp16(W2[(l>>4)*8+j][l&15])
constexpr size_t kBOffU16 = 960 * kARec * 2;
// wsC f32  [960][32]: n: {W3[n]*wgt, B2[n]} pairs
constexpr size_t kCOffF = (kBOffU16 + 960 * 512) / 2;
}

// Pack all weights into MFMA-fragment order. One wave per (g,f). 960 blocks.
__global__ __launch_bounds__(64) void pack_kernel(
    const float* __restrict__ cW1, const float* __restrict__ cB1,
    const float* __restrict__ cW2, const float* __restrict__ cB2,
    const float* __restrict__ cW3, const float* __restrict__ cB3,
    const float* __restrict__ sW1, const float* __restrict__ sB1,
    const float* __restrict__ sW2, const float* __restrict__ sB2,
    const float* __restrict__ sW3, const float* __restrict__ sB3,
    float* __restrict__ wsA, unsigned short* __restrict__ wsB,
    float* __restrict__ wsC) {
    const int rec = blockIdx.x;          // g*64 + f
    const int g = rec >> 6, f = rec & (kF - 1);
    const int l = threadIdx.x;
    const float *W1, *B1, *W2, *B2, *W3, *B3; float wgt; int base;
    if (g < kC) {
        base = g * kF + f;
        W1 = cW1; B1 = cB1; W2 = cW2; B2 = cB2; W3 = cW3; B3 = cB3; wgt = kWCat;
    } else {
        base = (g - kC) * kF + f;
        W1 = sW1; B1 = sB1; W2 = sW2; B2 = sB2; W3 = sW3; B3 = sB3; wgt = kWSub;
    }
    // B-fragment: lane l -> fp16(W2[k=(l>>4)*8+j][n=l&15]), j=0..7 (RNE cast).
    const int n = l & 15, kg = l >> 4;
    const float* w2p = W2 + base * (kH1 * kH2) + (kg * 8) * kH2 + n;
    half8 bw;
    #pragma unroll
    for (int j = 0; j < 8; ++j) bw[j] = (_Float16)w2p[j * kH2];
    *(half8*)(wsB + (size_t)rec * 512 + l * 8) = bw;

    float* ra = wsA + (size_t)rec * kARec;
    if (l < kH1) {
        ra[(l >> 3) * 16 + (l & 7)]     = W1[base * kH1 + l];
        ra[(l >> 3) * 16 + 8 + (l & 7)] = B1[base * kH1 + l];
    }
    if (l < kH2) {
        float2 v;
        v.x = W3[base * kH2 + l] * wgt;
        v.y = B2[base * kH2 + l];
        *(float2*)(wsC + (size_t)rec * 32 + l * 2) = v;
    }
    if (l == 0) ra[64] = wgt * B3[base];
}

namespace {
struct Frag { f32x4 w1a, w1b, b1a, b1b; half8 bw; float2 wc; float b3; };
}

// One block per (f, 64-row chunk): 64*32 = 2048 blocks, 4 waves each.
// Each wave owns one 16-row MFMA tile and loops 15 groups with register
// double-buffered packed weights (7 wide loads/group). fp16 MFMA operands.
__global__ __launch_bounds__(kThreads, 4) void nam_mfma(
    const float* __restrict__ x,
    const float* __restrict__ cbias, const float* __restrict__ sbias,
    const float* __restrict__ wsA, const unsigned short* __restrict__ wsB,
    const float* __restrict__ wsC, float* __restrict__ out) {
    const int f     = blockIdx.x & (kF - 1);
    const int chunk = blockIdx.x >> 6;
    const int wave  = threadIdx.x >> 6;
    const int lane  = threadIdx.x & 63;
    const int n  = lane & 15;
    const int kg = lane >> 4;
    const int rowbase = chunk * kRowsPerBlock + wave * 16;

    // x for my A-fragment row (m = n); same value across the 4 kg quads.
    const float xv = x[(size_t)(rowbase + n) * kF + f];

    const float* pA  = wsA + (size_t)f * kARec + kg * 16;
    const float* pA3 = wsA + (size_t)f * kARec + 64;
    const unsigned short* pB = wsB + (size_t)f * 512 + lane * 8;
    const float* pC  = wsC + (size_t)f * 32 + n * 2;

    auto load = [&](int g, Frag& fr) {
        const float* a = pA + (size_t)g * (kF * kARec);
        fr.w1a = *(const f32x4*)(a);
        fr.w1b = *(const f32x4*)(a + 4);
        fr.b1a = *(const f32x4*)(a + 8);
        fr.b1b = *(const f32x4*)(a + 12);
        fr.bw  = *(const half8*)(pB + (size_t)g * (kF * 512));
        fr.wc  = *(const float2*)(pC + (size_t)g * (kF * 32));
        fr.b3  = *(pA3 + (size_t)g * (kF * kARec));
    };

    float outp[4] = {0.f, 0.f, 0.f, 0.f};
    float bcon = 0.f;   // sum_g wgt*b3[g][f] (+ group biases for f==0)

    auto compute = [&](const Frag& fr) {
        // h1 = relu(x*w1+b1), packed to fp16 via hw pkrtz (2 vals/op).
        float h0 = fmaxf(fmaf(xv, fr.w1a.x, fr.b1a.x), 0.f);
        float h1 = fmaxf(fmaf(xv, fr.w1a.y, fr.b1a.y), 0.f);
        float h2 = fmaxf(fmaf(xv, fr.w1a.z, fr.b1a.z), 0.f);
        float h3 = fmaxf(fmaf(xv, fr.w1a.w, fr.b1a.w), 0.f);
        float h4 = fmaxf(fmaf(xv, fr.w1b.x, fr.b1b.x), 0.f);
        float h5 = fmaxf(fmaf(xv, fr.w1b.y, fr.b1b.y), 0.f);
        float h6 = fmaxf(fmaf(xv, fr.w1b.z, fr.b1b.z), 0.f);
        float h7 = fmaxf(fmaf(xv, fr.w1b.w, fr.b1b.w), 0.f);
        uint4v uu;
        uu.x = __builtin_bit_cast(unsigned, __builtin_amdgcn_cvt_pkrtz(h0, h1));
        uu.y = __builtin_bit_cast(unsigned, __builtin_amdgcn_cvt_pkrtz(h2, h3));
        uu.z = __builtin_bit_cast(unsigned, __builtin_amdgcn_cvt_pkrtz(h4, h5));
        uu.w = __builtin_bit_cast(unsigned, __builtin_amdgcn_cvt_pkrtz(h6, h7));
        half8 aw = __builtin_bit_cast(half8, uu);
        f32x4 c = { fr.wc.y, fr.wc.y, fr.wc.y, fr.wc.y };
        c = __builtin_amdgcn_mfma_f32_16x16x32_f16(aw, fr.bw, c, 0, 0, 0);
        // C/D: col=lane&15, row=kg*4+r (layout dtype-independent, m121)
        #pragma unroll
        for (int r = 0; r < 4; ++r)
            outp[r] = fmaf(fmaxf(c[r], 0.f), fr.wc.x, outp[r]);
        bcon += fr.b3;
    };

    Frag cur; load(0, cur);
    for (int g = 0; g < kG - 1; ++g) {
        Frag nxt; load(g + 1, nxt);
        compute(cur);
        cur = nxt;
    }
    compute(cur);

    if (f == 0) {   // fold the per-group biases in exactly once per row
        float bs = 0.f;
        #pragma unroll
        for (int i = 0; i < kC; ++i) bs = fmaf(cbias[i], kWCat, bs);
        #pragma unroll
        for (int i = 0; i < kS; ++i) bs = fmaf(sbias[i], kWSub, bs);
        bcon += bs;
    }

    // Reduce over the 16 h2-columns (lanes with same kg), one atomic per row.
    #pragma unroll
    for (int r = 0; r < 4; ++r) {
        float v = outp[r] + ((n == 0) ? bcon : 0.f);
        v += __shfl_xor(v, 1);
        v += __shfl_xor(v, 2);
        v += __shfl_xor(v, 4);
        v += __shfl_xor(v, 8);
        if (n == 0) atomicAdd(&out[rowbase + kg * 4 + r], v);
    }
}

extern "C" void kernel_launch(void* const* d_in, const int* in_sizes, int n_in,
                              void* d_out, int out_size, void* d_ws, size_t ws_size,
                              hipStream_t stream) {
    const float* x     = (const float*)d_in[0];
    const float* cW1   = (const float*)d_in[1];
    const float* cB1   = (const float*)d_in[2];
    const float* cW2   = (const float*)d_in[3];
    const float* cB2   = (const float*)d_in[4];
    const float* cW3   = (const float*)d_in[5];
    const float* cB3   = (const float*)d_in[6];
    const float* cbias = (const float*)d_in[7];
    const float* sW1   = (const float*)d_in[8];
    const float* sB1   = (const float*)d_in[9];
    const float* sW2   = (const float*)d_in[10];
    const float* sB2   = (const float*)d_in[11];
    const float* sW3   = (const float*)d_in[12];
    const float* sB3   = (const float*)d_in[13];
    const float* sbias = (const float*)d_in[14];
    float* out = (float*)d_out;

    float* wsA = (float*)d_ws;
    unsigned short* wsB = (unsigned short*)d_ws + kBOffU16;
    float* wsC = (float*)d_ws + kCOffF;
    (void)ws_size; (void)n_in; (void)in_sizes;

    hipMemsetAsync(out, 0, (size_t)out_size * sizeof(float), stream);
    pack_kernel<<<kG * kF, 64, 0, stream>>>(cW1, cB1, cW2, cB2, cW3, cB3,
                                            sW1, sB1, sW2, sB2, sW3, sB3,
                                            wsA, wsB, wsC);
    nam_mfma<<<kF * kChunks, kThreads, 0, stream>>>(
        x, cbias, sbias, wsA, wsB, wsC, out);
}

// Round 7
// 36.769 us; speedup vs baseline: 1.2613x; 1.2613x over previous
//
#include <hip/hip_runtime.h>

typedef __attribute__((ext_vector_type(8))) _Float16 half8;
typedef __attribute__((ext_vector_type(4))) float f32x4;
typedef __attribute__((ext_vector_type(4))) unsigned int uint4v;

namespace {
constexpr int kB = 2048;
constexpr int kF = 64;
constexpr int kC = 10;
constexpr int kS = 5;
constexpr int kG = kC + kS;          // 15 groups
constexpr int kH1 = 32;
constexpr int kH2 = 16;
constexpr float kWCat = 0.7f / kC;
constexpr float kWSub = 0.3f / kS;
constexpr int kThreads = 256;        // 4 waves
constexpr int kRowsPerBlock = 128;   // 4 waves x 2 tiles x 16 rows
constexpr int kChunks = kB / kRowsPerBlock;   // 16 -> grid = 64*16 = 1024
}

// Phase 1: per-(f, row-chunk) block. Stage this f's weights (all 15 groups)
// into LDS once (coalesced), then fp16-MFMA over 128 rows. Writes per-f
// partial sums to pp[f][row] with plain stores (no atomics, no init needed).
__global__ __launch_bounds__(kThreads, 4) void nam_stage(
    const float* __restrict__ x,
    const float* __restrict__ cW1, const float* __restrict__ cB1,
    const float* __restrict__ cW2, const float* __restrict__ cB2,
    const float* __restrict__ cW3, const float* __restrict__ cB3,
    const float* __restrict__ sW1, const float* __restrict__ sB1,
    const float* __restrict__ sW2, const float* __restrict__ sB2,
    const float* __restrict__ sW3, const float* __restrict__ sB3,
    float* __restrict__ pp) {
    const int f     = blockIdx.x & (kF - 1);
    const int chunk = blockIdx.x >> 6;
    const int tid   = threadIdx.x;

    // LDS staging of all 15 groups' weights for this f (~25 KB).
    __shared__ float    lW1B1[kG][4][16];   // [g][kg][0..7 w1, 8..15 b1]
    __shared__ _Float16 lW2T[kG][16][40];   // [g][n][k] f16, padded to 40
    __shared__ float2   lWC[kG][16];        // {W3*wgt, B2}
    __shared__ float    lB3[kG];            // wgt * b3

    for (int i = tid; i < kG * 64; i += kThreads) {
        const int g = i >> 6, r = i & 63;
        const int kg = r >> 4, e = r & 15;
        const int base = ((g < kC) ? (g * kF + f) : ((g - kC) * kF + f)) * kH1
                         + kg * 8 + (e & 7);
        const float* src = (e < 8) ? ((g < kC) ? cW1 : sW1)
                                   : ((g < kC) ? cB1 : sB1);
        lW1B1[g][kg][e] = src[base];
    }
    for (int i = tid; i < kG * 512; i += kThreads) {
        const int g = i >> 9, e = i & 511;
        const int k = e >> 4, n = e & 15;
        const float* src = (g < kC) ? (cW2 + (size_t)(g * kF + f) * 512)
                                    : (sW2 + (size_t)((g - kC) * kF + f) * 512);
        lW2T[g][n][k] = (_Float16)src[e];
    }
    for (int i = tid; i < kG * kH2; i += kThreads) {
        const int g = i >> 4, nn = i & 15;
        const int base = ((g < kC) ? (g * kF + f) : ((g - kC) * kF + f)) * kH2 + nn;
        float2 v;
        v.x = ((g < kC) ? cW3 : sW3)[base] * ((g < kC) ? kWCat : kWSub);
        v.y = ((g < kC) ? cB2 : sB2)[base];
        lWC[g][nn] = v;
    }
    if (tid < kG) {
        const int g = tid;
        lB3[g] = (g < kC) ? kWCat * cB3[g * kF + f]
                          : kWSub * sB3[(g - kC) * kF + f];
    }
    __syncthreads();

    const int wave = tid >> 6;
    const int lane = tid & 63;
    const int n  = lane & 15;
    const int kg = lane >> 4;
    const int rowbase = chunk * kRowsPerBlock + wave * 32;

    const float xv0 = x[(size_t)(rowbase + n) * kF + f];
    const float xv1 = x[(size_t)(rowbase + 16 + n) * kF + f];

    float outp[2][4] = {{0.f, 0.f, 0.f, 0.f}, {0.f, 0.f, 0.f, 0.f}};
    float bcon = 0.f;

    #pragma unroll 2
    for (int g = 0; g < kG; ++g) {
        const f32x4 w1a = *(const f32x4*)&lW1B1[g][kg][0];
        const f32x4 w1b = *(const f32x4*)&lW1B1[g][kg][4];
        const f32x4 b1a = *(const f32x4*)&lW1B1[g][kg][8];
        const f32x4 b1b = *(const f32x4*)&lW1B1[g][kg][12];
        const half8 bw  = *(const half8*)&lW2T[g][n][kg * 8];
        const float2 wc = lWC[g][n];
        bcon += lB3[g];

        #pragma unroll
        for (int t = 0; t < 2; ++t) {
            const float xv = t ? xv1 : xv0;
            float h0 = fmaxf(fmaf(xv, w1a.x, b1a.x), 0.f);
            float h1 = fmaxf(fmaf(xv, w1a.y, b1a.y), 0.f);
            float h2 = fmaxf(fmaf(xv, w1a.z, b1a.z), 0.f);
            float h3 = fmaxf(fmaf(xv, w1a.w, b1a.w), 0.f);
            float h4 = fmaxf(fmaf(xv, w1b.x, b1b.x), 0.f);
            float h5 = fmaxf(fmaf(xv, w1b.y, b1b.y), 0.f);
            float h6 = fmaxf(fmaf(xv, w1b.z, b1b.z), 0.f);
            float h7 = fmaxf(fmaf(xv, w1b.w, b1b.w), 0.f);
            uint4v uu;
            uu.x = __builtin_bit_cast(unsigned, __builtin_amdgcn_cvt_pkrtz(h0, h1));
            uu.y = __builtin_bit_cast(unsigned, __builtin_amdgcn_cvt_pkrtz(h2, h3));
            uu.z = __builtin_bit_cast(unsigned, __builtin_amdgcn_cvt_pkrtz(h4, h5));
            uu.w = __builtin_bit_cast(unsigned, __builtin_amdgcn_cvt_pkrtz(h6, h7));
            const half8 aw = __builtin_bit_cast(half8, uu);
            f32x4 c = { wc.y, wc.y, wc.y, wc.y };
            c = __builtin_amdgcn_mfma_f32_16x16x32_f16(aw, bw, c, 0, 0, 0);
            // C/D: col = lane&15, row = kg*4 + r
            #pragma unroll
            for (int r = 0; r < 4; ++r)
                outp[t][r] = fmaf(fmaxf(c[r], 0.f), wc.x, outp[t][r]);
        }
    }

    // Reduce over the 16 h2-columns (lanes sharing kg); n==0 lanes store
    // this f's partial (plus per-f b3 constant) to pp[f][row].
    #pragma unroll
    for (int t = 0; t < 2; ++t)
        #pragma unroll
        for (int r = 0; r < 4; ++r) {
            float v = outp[t][r];
            v += __shfl_xor(v, 1);
            v += __shfl_xor(v, 2);
            v += __shfl_xor(v, 4);
            v += __shfl_xor(v, 8);
            if (n == 0)
                pp[(size_t)f * kB + rowbase + t * 16 + kg * 4 + r] = v + bcon;
        }
}

// Phase 2: out[b] = sum_f pp[f][b] + weighted group-bias constant.
__global__ __launch_bounds__(kThreads) void reduce_kernel(
    const float* __restrict__ pp,
    const float* __restrict__ cbias, const float* __restrict__ sbias,
    float* __restrict__ out) {
    const int b = blockIdx.x * kThreads + threadIdx.x;
    float s = 0.f;
    #pragma unroll 8
    for (int f = 0; f < kF; ++f) s += pp[(size_t)f * kB + b];   // coalesced per f
    float bs = 0.f;
    #pragma unroll
    for (int i = 0; i < kC; ++i) bs = fmaf(cbias[i], kWCat, bs);
    #pragma unroll
    for (int i = 0; i < kS; ++i) bs = fmaf(sbias[i], kWSub, bs);
    out[b] = s + bs;
}

extern "C" void kernel_launch(void* const* d_in, const int* in_sizes, int n_in,
                              void* d_out, int out_size, void* d_ws, size_t ws_size,
                              hipStream_t stream) {
    const float* x     = (const float*)d_in[0];
    const float* cW1   = (const float*)d_in[1];
    const float* cB1   = (const float*)d_in[2];
    const float* cW2   = (const float*)d_in[3];
    const float* cB2   = (const float*)d_in[4];
    const float* cW3   = (const float*)d_in[5];
    const float* cB3   = (const float*)d_in[6];
    const float* cbias = (const float*)d_in[7];
    const float* sW1   = (const float*)d_in[8];
    const float* sB1   = (const float*)d_in[9];
    const float* sW2   = (const float*)d_in[10];
    const float* sB2   = (const float*)d_in[11];
    const float* sW3   = (const float*)d_in[12];
    const float* sB3   = (const float*)d_in[13];
    const float* sbias = (const float*)d_in[14];
    float* out = (float*)d_out;
    float* pp  = (float*)d_ws;           // 64*2048 floats = 512 KB partials
    (void)ws_size; (void)n_in; (void)in_sizes; (void)out_size;

    nam_stage<<<kF * kChunks, kThreads, 0, stream>>>(
        x, cW1, cB1, cW2, cB2, cW3, cB3,
        sW1, sB1, sW2, sB2, sW3, sB3, pp);
    reduce_kernel<<<kB / kThreads, kThreads, 0, stream>>>(pp, cbias, sbias, out);
}